// Round 4
// baseline (243.137 us; speedup 1.0000x reference)
//
#include <hip/hip_runtime.h>

// dense_image_warp: B=8, H=512, W=512, C=16, fp32.
//
// R3: 2D tiling + XCD-chunked swizzle to kill gather read-amplification.
// Gathers read 256B/pixel vs 64B unique (4x). Old layout (64x1 row-segment
// blocks + round-robin XCD dispatch) pushed all vertical corner reuse out to
// L3 (~8 TB/s demand => binder). New layout:
//   - block = 1024 threads = 16x16 pixel tile (x4 float4 channel groups).
//     Input footprint ~19x19 px * 64B ~ 23KB -> fits 32KB L1; most corner
//     re-reads become L1 hits.
//   - swizzle: logical = (bid%8)*1024 + bid/8  => XCD k (round-robin bid%8)
//     processes batch k in tile-row-major order; cross-tile halo reuse stays
//     in that XCD's 4MB L2 (window ~600KB).
// tid-in-block bits: [yy:4][xx:4][cg:2]; a wave = one 16-px tile row =
// 1KB contiguous store, 128B contiguous flow load.

__global__ __launch_bounds__(1024) void warp_kernel(
    const float* __restrict__ img,
    const float* __restrict__ flow,
    float* __restrict__ out)
{
    // XCD-chunked bijective swizzle (8192 blocks, 8 XCDs)
    const int bid = blockIdx.x;
    const int logical = ((bid & 7) << 10) + (bid >> 3);

    const int tx = logical & 31;          // tile x: 0..31
    const int ty = (logical >> 5) & 31;   // tile y: 0..31
    const int b  = logical >> 10;         // batch: 0..7

    const int t  = threadIdx.x;
    const int cg = t & 3;
    const int xx = (t >> 2) & 15;
    const int yy = t >> 6;

    const int x = (tx << 4) + xx;
    const int y = (ty << 4) + yy;

    const int pix = (((b << 9) + y) << 9) + x;   // (b*512 + y)*512 + x

    const float2 f = ((const float2*)flow)[pix];
    const float qy = (float)y - f.x;
    const float qx = (float)x - f.y;

    float fy = floorf(qy); fy = fminf(fmaxf(fy, 0.0f), 510.0f);
    float fx = floorf(qx); fx = fminf(fmaxf(fx, 0.0f), 510.0f);
    const float ay = fminf(fmaxf(qy - fy, 0.0f), 1.0f);
    const float ax = fminf(fmaxf(qx - fx, 0.0f), 1.0f);
    const int iy = (int)fy;
    const int ix = (int)fx;

    const float* p = img + ((size_t)((((b << 9) + iy) << 9) + ix)) * 16 + (cg << 2);

    const float4 tl = *(const float4*)(p);
    const float4 tr = *(const float4*)(p + 16);
    const float4 bl = *(const float4*)(p + 512 * 16);
    const float4 br = *(const float4*)(p + 512 * 16 + 16);

    float4 r;
    {
        float t0, u0;
        t0 = tl.x + ax * (tr.x - tl.x);
        u0 = bl.x + ax * (br.x - bl.x);
        r.x = t0 + ay * (u0 - t0);
        t0 = tl.y + ax * (tr.y - tl.y);
        u0 = bl.y + ax * (br.y - bl.y);
        r.y = t0 + ay * (u0 - t0);
        t0 = tl.z + ax * (tr.z - tl.z);
        u0 = bl.z + ax * (br.z - bl.z);
        r.z = t0 + ay * (u0 - t0);
        t0 = tl.w + ax * (tr.w - tl.w);
        u0 = bl.w + ax * (br.w - bl.w);
        r.w = t0 + ay * (u0 - t0);
    }

    ((float4*)out)[(pix << 2) + cg] = r;
}

extern "C" void kernel_launch(void* const* d_in, const int* in_sizes, int n_in,
                              void* d_out, int out_size, void* d_ws, size_t ws_size,
                              hipStream_t stream) {
    const float* img  = (const float*)d_in[0];
    const float* flow = (const float*)d_in[1];
    float* out = (float*)d_out;

    const int block = 1024;                      // 16x16 pixel tile, 4 cg/pixel
    const int grid = (8 * 512 * 512 * 4) / block; // 8192
    warp_kernel<<<grid, block, 0, stream>>>(img, flow, out);
}